// Round 2
// baseline (370.009 us; speedup 1.0000x reference)
//
#include <hip/hip_runtime.h>
#include <math.h>
#include <float.h>

#define BN 2
#define NP 1024
#define NC 81
#define ND 100
#define MAXC 8192
#define SCORE_T 0.05f
#define NMS_T 0.5f
#define NEGV -1e30f
#define BBOX_CLIP 4.135166556742356f   // log(1000/16)

// ---------------- Kernel 1: softmax stats (max + sumexp per proposal) ----------------
__global__ __launch_bounds__(256) void softmax_stats_kernel(
    const float* __restrict__ logits, float* __restrict__ mx, float* __restrict__ se,
    int* __restrict__ cnt)
{
    int g = blockIdx.x * blockDim.x + threadIdx.x;
    if (g == 0) { cnt[0] = 0; cnt[1] = 0; }
    if (g >= BN * NP) return;
    const float* row = logits + (size_t)g * NC;
    float m = -FLT_MAX;
    for (int i = 0; i < NC; ++i) m = fmaxf(m, row[i]);
    float s = 0.f;
    for (int i = 0; i < NC; ++i) s += expf(row[i] - m);
    mx[g] = m;
    se[g] = s;
}

// ---------------- Kernel 2: per-(image,class) filter + sort + decode + NMS ----------------
__global__ __launch_bounds__(256) void per_class_nms_kernel(
    const float* __restrict__ logits, const float* __restrict__ regress,
    const float* __restrict__ props, const float* __restrict__ mx,
    const float* __restrict__ se, int* __restrict__ cnt,
    float* __restrict__ g_score, float* __restrict__ g_box, int* __restrict__ g_flat)
{
    const int b   = blockIdx.x / (NC - 1);
    const int cls = blockIdx.x % (NC - 1);   // 0..79
    const int c   = cls + 1;                 // class index in [1, 80]
    const int tid = threadIdx.x;

    __shared__ float s_score[NP];
    __shared__ int   s_idx[NP];
    __shared__ float s_x1[NP], s_y1[NP], s_x2[NP], s_y2[NP], s_area[NP];
    __shared__ int   s_keep[NP];
    __shared__ int   s_cnt;

    if (tid == 0) s_cnt = 0;
    __syncthreads();

    // --- compact candidates with prob > SCORE_T ---
    for (int n = tid; n < NP; n += 256) {
        int g = b * NP + n;
        float p = expf(logits[(size_t)g * NC + c] - mx[g]) / se[g];
        if (p > SCORE_T) {
            int k = atomicAdd(&s_cnt, 1);
            s_score[k] = p;
            s_idx[k]   = n;
        }
    }
    __syncthreads();
    const int M = s_cnt;
    if (M == 0) return;

    int Mp = 1; while (Mp < M) Mp <<= 1;

    for (int i = M + tid; i < Mp; i += 256) { s_score[i] = -FLT_MAX; s_idx[i] = NP + i; }
    __syncthreads();

    // --- bitonic sort, descending by score ---
    for (int k = 2; k <= Mp; k <<= 1) {
        for (int j = k >> 1; j > 0; j >>= 1) {
            for (int i = tid; i < Mp; i += 256) {
                int ixj = i ^ j;
                if (ixj > i) {
                    bool desc = ((i & k) == 0);
                    float si = s_score[i], sj = s_score[ixj];
                    if (desc ? (si < sj) : (si > sj)) {
                        s_score[i] = sj; s_score[ixj] = si;
                        int t = s_idx[i]; s_idx[i] = s_idx[ixj]; s_idx[ixj] = t;
                    }
                }
            }
            __syncthreads();
        }
    }

    // --- decode boxes for the M live candidates (reference op order) ---
    for (int i = tid; i < M; i += 256) {
        int n = s_idx[i];
        const float* pr = props + ((size_t)b * NP + n) * 4;
        float p0 = pr[0], p1 = pr[1], p2 = pr[2], p3 = pr[3];
        float w  = p2 - p0 + 1.0f, h = p3 - p1 + 1.0f;
        float cx = p0 + 0.5f * w,  cy = p1 + 0.5f * h;
        const float* rl = regress + (((size_t)b * NP + n) * NC + c) * 4;
        float dx = rl[0] / 10.0f, dy = rl[1] / 10.0f;
        float dw = fminf(rl[2] / 5.0f, BBOX_CLIP);
        float dh = fminf(rl[3] / 5.0f, BBOX_CLIP);
        float pcx = dx * w + cx, pcy = dy * h + cy;
        float pw  = expf(dw) * w, ph = expf(dh) * h;
        float x1 = pcx - 0.5f * pw, y1 = pcy - 0.5f * ph;
        float x2 = pcx + 0.5f * pw - 1.0f, y2 = pcy + 0.5f * ph - 1.0f;
        x1 = fminf(fmaxf(x1, 0.f), 1023.f);
        y1 = fminf(fmaxf(y1, 0.f), 1023.f);
        x2 = fminf(fmaxf(x2, 0.f), 1023.f);
        y2 = fminf(fmaxf(y2, 0.f), 1023.f);
        s_x1[i] = x1; s_y1[i] = y1; s_x2[i] = x2; s_y2[i] = y2;
        s_area[i] = (x2 - x1 + 1.f) * (y2 - y1 + 1.f);
        s_keep[i] = 1;
    }
    __syncthreads();

    // --- greedy NMS: i sequential, suppression parallel ---
    for (int i = 0; i < M; ++i) {
        if (s_keep[i]) {
            float x1i = s_x1[i], y1i = s_y1[i], x2i = s_x2[i], y2i = s_y2[i], ai = s_area[i];
            for (int j = i + 1 + tid; j < M; j += 256) {
                float lx = fmaxf(x1i, s_x1[j]);
                float ly = fmaxf(y1i, s_y1[j]);
                float rx = fminf(x2i, s_x2[j]);
                float ry = fminf(y2i, s_y2[j]);
                float wd = fmaxf(rx - lx + 1.f, 0.f);
                float ht = fmaxf(ry - ly + 1.f, 0.f);
                float inter = wd * ht;
                float iou = inter / (ai + s_area[j] - inter);
                if (iou > NMS_T) s_keep[j] = 0;
            }
        }
        __syncthreads();
    }

    // --- append survivors to the per-image candidate list ---
    for (int i = tid; i < M; i += 256) {
        if (s_keep[i]) {
            int pos = atomicAdd(&cnt[b], 1);
            if (pos < MAXC) {
                size_t o = (size_t)b * MAXC + pos;
                g_score[o]     = s_score[i];
                g_flat[o]      = cls * NP + s_idx[i];
                g_box[o*4 + 0] = s_x1[i];
                g_box[o*4 + 1] = s_y1[i];
                g_box[o*4 + 2] = s_x2[i];
                g_box[o*4 + 3] = s_y2[i];
            }
        }
    }
}

// ---------------- Kernel 3: per-image top-100 (sequential argmax, tie-break on flat idx) ----------------
__global__ __launch_bounds__(256) void topk_kernel(
    const int* __restrict__ cnt, float* __restrict__ g_score,
    const float* __restrict__ g_box, const int* __restrict__ g_flat,
    float* __restrict__ out)
{
    const int b = blockIdx.x;
    const int tid = threadIdx.x;
    int K = cnt[b]; if (K > MAXC) K = MAXC;

    __shared__ float rs[256];
    __shared__ int   rf[256];
    __shared__ int   rp[256];

    for (int d = 0; d < ND; ++d) {
        float bs = -FLT_MAX; int bf = 0x7fffffff; int bp = -1;
        for (int t = tid; t < K; t += 256) {
            float s = g_score[(size_t)b * MAXC + t];
            int   f = g_flat[(size_t)b * MAXC + t];
            if (s > bs || (s == bs && f < bf)) { bs = s; bf = f; bp = t; }
        }
        rs[tid] = bs; rf[tid] = bf; rp[tid] = bp;
        __syncthreads();
        for (int off = 128; off > 0; off >>= 1) {
            if (tid < off) {
                if (rs[tid+off] > rs[tid] ||
                    (rs[tid+off] == rs[tid] && rf[tid+off] < rf[tid])) {
                    rs[tid] = rs[tid+off]; rf[tid] = rf[tid+off]; rp[tid] = rp[tid+off];
                }
            }
            __syncthreads();
        }
        if (tid == 0) {
            float bsc = rs[0]; int bfl = rf[0]; int bpo = rp[0];
            float* ob = out + ((size_t)b * ND + d) * 4;
            float* os = out + (size_t)BN * ND * 4 + b * ND + d;
            float* ol = out + (size_t)BN * ND * 5 + b * ND + d;
            if (bpo >= 0 && bsc > NEGV * 0.5f) {
                size_t o = (size_t)b * MAXC + bpo;
                ob[0] = g_box[o*4 + 0];
                ob[1] = g_box[o*4 + 1];
                ob[2] = g_box[o*4 + 2];
                ob[3] = g_box[o*4 + 3];
                *os = bsc;
                *ol = (float)(bfl / NP + 1);
                g_score[o] = -FLT_MAX;   // consume
            } else {
                ob[0] = 0.f; ob[1] = 0.f; ob[2] = 0.f; ob[3] = 0.f;
                *os = 0.f;
                *ol = -1.f;
            }
        }
        __syncthreads();
    }
}

extern "C" void kernel_launch(void* const* d_in, const int* in_sizes, int n_in,
                              void* d_out, int out_size, void* d_ws, size_t ws_size,
                              hipStream_t stream) {
    const float* logits  = (const float*)d_in[0];   // [B, N, C]
    const float* regress = (const float*)d_in[1];   // [B, N, C*4]
    const float* props   = (const float*)d_in[2];   // [B, N, 4]
    float* out = (float*)d_out;                     // boxes(800) | scores(200) | labels(200)

    // Workspace layout (NO overlap — round 1 bug was cnt aliasing g_score):
    //   [0      , 8192 )  mx   : BN*NP floats
    //   [8192   , 16384)  se   : BN*NP floats
    //   [16384  , 16392)  cnt  : 2 ints
    //   [16640  , 82176)  g_score : BN*MAXC floats   (64 KB)
    //   [82176  , 147712) g_flat  : BN*MAXC ints     (64 KB)
    //   [147712 , 409856) g_box   : BN*MAXC*4 floats (256 KB)
    char* ws = (char*)d_ws;
    float* mx      = (float*)(ws);
    float* se      = (float*)(ws + 8192);
    int*   cnt     = (int*)  (ws + 16384);
    float* g_score = (float*)(ws + 16640);
    int*   g_flat  = (int*)  (ws + 16640 + BN * MAXC * 4);
    float* g_box   = (float*)(ws + 16640 + BN * MAXC * 8);

    hipLaunchKernelGGL(softmax_stats_kernel, dim3((BN * NP + 255) / 256), dim3(256), 0, stream,
                       logits, mx, se, cnt);
    hipLaunchKernelGGL(per_class_nms_kernel, dim3(BN * (NC - 1)), dim3(256), 0, stream,
                       logits, regress, props, mx, se, cnt, g_score, g_box, g_flat);
    hipLaunchKernelGGL(topk_kernel, dim3(BN), dim3(256), 0, stream,
                       cnt, g_score, g_box, g_flat, out);
}

// Round 3
// 154.272 us; speedup vs baseline: 2.3984x; 2.3984x over previous
//
#include <hip/hip_runtime.h>
#include <math.h>
#include <float.h>

#define BN 2
#define NP 1024
#define NC 81
#define ND 100
#define MAXC 8192
#define SCORE_T 0.05f
#define NMS_T 0.5f
#define BBOX_CLIP 4.135166556742356f   // log(1000/16)

// Decode one box, identical op order everywhere so kernel2/kernel3 results are bit-equal.
__device__ __forceinline__ void decode_box(
    const float* __restrict__ props, const float* __restrict__ regress,
    int b, int n, int c, float& x1, float& y1, float& x2, float& y2)
{
    const float* pr = props + ((size_t)b * NP + n) * 4;
    float p0 = pr[0], p1 = pr[1], p2 = pr[2], p3 = pr[3];
    float w  = p2 - p0 + 1.0f, h = p3 - p1 + 1.0f;
    float cx = p0 + 0.5f * w,  cy = p1 + 0.5f * h;
    const float* rl = regress + (((size_t)b * NP + n) * NC + c) * 4;
    float dx = rl[0] / 10.0f, dy = rl[1] / 10.0f;
    float dw = fminf(rl[2] / 5.0f, BBOX_CLIP);
    float dh = fminf(rl[3] / 5.0f, BBOX_CLIP);
    float pcx = dx * w + cx, pcy = dy * h + cy;
    float pw  = expf(dw) * w, ph = expf(dh) * h;
    x1 = pcx - 0.5f * pw; y1 = pcy - 0.5f * ph;
    x2 = pcx + 0.5f * pw - 1.0f; y2 = pcy + 0.5f * ph - 1.0f;
    x1 = fminf(fmaxf(x1, 0.f), 1023.f);
    y1 = fminf(fmaxf(y1, 0.f), 1023.f);
    x2 = fminf(fmaxf(x2, 0.f), 1023.f);
    y2 = fminf(fmaxf(y2, 0.f), 1023.f);
}

// ---------------- Kernel 1: softmax stats (max + sumexp per proposal) ----------------
__global__ __launch_bounds__(256) void softmax_stats_kernel(
    const float* __restrict__ logits, float* __restrict__ mx, float* __restrict__ se,
    int* __restrict__ cnt)
{
    int g = blockIdx.x * blockDim.x + threadIdx.x;
    if (g == 0) { cnt[0] = 0; cnt[1] = 0; }
    if (g >= BN * NP) return;
    const float* row = logits + (size_t)g * NC;
    float m = -FLT_MAX;
    for (int i = 0; i < NC; ++i) m = fmaxf(m, row[i]);
    float s = 0.f;
    for (int i = 0; i < NC; ++i) s += expf(row[i] - m);
    mx[g] = m;
    se[g] = s;
}

// ---------------- Kernel 2: per-(image,class) filter + sort + decode + NMS ----------------
// Survivors are appended as packed keys: (score_bits << 32) | (~flat_idx).
__global__ __launch_bounds__(256) void per_class_nms_kernel(
    const float* __restrict__ logits, const float* __restrict__ regress,
    const float* __restrict__ props, const float* __restrict__ mx,
    const float* __restrict__ se, int* __restrict__ cnt,
    unsigned long long* __restrict__ g_key)
{
    const int b   = blockIdx.x / (NC - 1);
    const int cls = blockIdx.x % (NC - 1);   // 0..79
    const int c   = cls + 1;                 // class index in [1, 80]
    const int tid = threadIdx.x;

    __shared__ float s_score[NP];
    __shared__ int   s_idx[NP];
    __shared__ float s_x1[NP], s_y1[NP], s_x2[NP], s_y2[NP], s_area[NP];
    __shared__ int   s_keep[NP];
    __shared__ int   s_cnt;

    if (tid == 0) s_cnt = 0;
    __syncthreads();

    // --- compact candidates with prob > SCORE_T ---
    for (int n = tid; n < NP; n += 256) {
        int g = b * NP + n;
        float p = expf(logits[(size_t)g * NC + c] - mx[g]) / se[g];
        if (p > SCORE_T) {
            int k = atomicAdd(&s_cnt, 1);
            s_score[k] = p;
            s_idx[k]   = n;
        }
    }
    __syncthreads();
    const int M = s_cnt;
    if (M == 0) return;

    int Mp = 1; while (Mp < M) Mp <<= 1;

    for (int i = M + tid; i < Mp; i += 256) { s_score[i] = -FLT_MAX; s_idx[i] = NP + i; }
    __syncthreads();

    // --- bitonic sort, descending by score ---
    for (int k = 2; k <= Mp; k <<= 1) {
        for (int j = k >> 1; j > 0; j >>= 1) {
            for (int i = tid; i < Mp; i += 256) {
                int ixj = i ^ j;
                if (ixj > i) {
                    bool desc = ((i & k) == 0);
                    float si = s_score[i], sj = s_score[ixj];
                    if (desc ? (si < sj) : (si > sj)) {
                        s_score[i] = sj; s_score[ixj] = si;
                        int t = s_idx[i]; s_idx[i] = s_idx[ixj]; s_idx[ixj] = t;
                    }
                }
            }
            __syncthreads();
        }
    }

    // --- decode boxes for the M live candidates ---
    for (int i = tid; i < M; i += 256) {
        int n = s_idx[i];
        float x1, y1, x2, y2;
        decode_box(props, regress, b, n, c, x1, y1, x2, y2);
        s_x1[i] = x1; s_y1[i] = y1; s_x2[i] = x2; s_y2[i] = y2;
        s_area[i] = (x2 - x1 + 1.f) * (y2 - y1 + 1.f);
        s_keep[i] = 1;
    }
    __syncthreads();

    // --- greedy NMS: i sequential, suppression parallel ---
    for (int i = 0; i < M; ++i) {
        if (s_keep[i]) {
            float x1i = s_x1[i], y1i = s_y1[i], x2i = s_x2[i], y2i = s_y2[i], ai = s_area[i];
            for (int j = i + 1 + tid; j < M; j += 256) {
                float lx = fmaxf(x1i, s_x1[j]);
                float ly = fmaxf(y1i, s_y1[j]);
                float rx = fminf(x2i, s_x2[j]);
                float ry = fminf(y2i, s_y2[j]);
                float wd = fmaxf(rx - lx + 1.f, 0.f);
                float ht = fmaxf(ry - ly + 1.f, 0.f);
                float inter = wd * ht;
                float iou = inter / (ai + s_area[j] - inter);
                if (iou > NMS_T) s_keep[j] = 0;
            }
        }
        __syncthreads();
    }

    // --- append survivor keys to the per-image list ---
    for (int i = tid; i < M; i += 256) {
        if (s_keep[i]) {
            int pos = atomicAdd(&cnt[b], 1);
            if (pos < MAXC) {
                unsigned int sb = __float_as_uint(s_score[i]);
                unsigned int f  = (unsigned int)(cls * NP + s_idx[i]);
                g_key[(size_t)b * MAXC + pos] =
                    ((unsigned long long)sb << 32) | (unsigned long long)(0xFFFFFFFFu - f);
            }
        }
    }
}

// ---------------- Kernel 3: per-image top-100 via LDS bitonic sort of packed keys ----------------
__global__ __launch_bounds__(1024) void topk_kernel(
    const int* __restrict__ cnt, const unsigned long long* __restrict__ g_key,
    const float* __restrict__ props, const float* __restrict__ regress,
    float* __restrict__ out)
{
    const int b = blockIdx.x;
    const int tid = threadIdx.x;

    __shared__ unsigned long long s_key[MAXC];   // 64 KB

    int K = cnt[b]; if (K > MAXC) K = MAXC;
    int Kp = 256; while (Kp < K) Kp <<= 1;       // >= 256 so top-ND slots always exist

    for (int i = tid; i < Kp; i += 1024)
        s_key[i] = (i < K) ? g_key[(size_t)b * MAXC + i] : 0ull;
    __syncthreads();

    // bitonic sort, descending (key packs score desc + flat asc tie-break)
    for (int k = 2; k <= Kp; k <<= 1) {
        for (int j = k >> 1; j > 0; j >>= 1) {
            for (int i = tid; i < Kp; i += 1024) {
                int ixj = i ^ j;
                if (ixj > i) {
                    bool desc = ((i & k) == 0);
                    unsigned long long a = s_key[i], c2 = s_key[ixj];
                    if (desc ? (a < c2) : (a > c2)) { s_key[i] = c2; s_key[ixj] = a; }
                }
            }
            __syncthreads();
        }
    }

    // emit top-ND: re-decode winning boxes (bit-identical arithmetic to kernel 2)
    for (int d = tid; d < ND; d += 1024) {
        unsigned long long key = s_key[d];
        float score = __uint_as_float((unsigned int)(key >> 32));
        float* ob = out + ((size_t)b * ND + d) * 4;
        float* os = out + (size_t)BN * ND * 4 + b * ND + d;
        float* ol = out + (size_t)BN * ND * 5 + b * ND + d;
        if (score > 0.f) {
            unsigned int f = 0xFFFFFFFFu - (unsigned int)(key & 0xFFFFFFFFu);
            int cls = f / NP, n = f % NP;
            float x1, y1, x2, y2;
            decode_box(props, regress, b, n, cls + 1, x1, y1, x2, y2);
            ob[0] = x1; ob[1] = y1; ob[2] = x2; ob[3] = y2;
            *os = score;
            *ol = (float)(cls + 1);
        } else {
            ob[0] = 0.f; ob[1] = 0.f; ob[2] = 0.f; ob[3] = 0.f;
            *os = 0.f;
            *ol = -1.f;
        }
    }
}

extern "C" void kernel_launch(void* const* d_in, const int* in_sizes, int n_in,
                              void* d_out, int out_size, void* d_ws, size_t ws_size,
                              hipStream_t stream) {
    const float* logits  = (const float*)d_in[0];   // [B, N, C]
    const float* regress = (const float*)d_in[1];   // [B, N, C*4]
    const float* props   = (const float*)d_in[2];   // [B, N, 4]
    float* out = (float*)d_out;                     // boxes(800) | scores(200) | labels(200)

    // Workspace layout (no overlap):
    //   [0      , 8192 )  mx    : BN*NP floats
    //   [8192   , 16384)  se    : BN*NP floats
    //   [16384  , 16392)  cnt   : 2 ints
    //   [16640  , 147712) g_key : BN*MAXC u64 (128 KB)
    char* ws = (char*)d_ws;
    float* mx  = (float*)(ws);
    float* se  = (float*)(ws + 8192);
    int*   cnt = (int*)  (ws + 16384);
    unsigned long long* g_key = (unsigned long long*)(ws + 16640);

    hipLaunchKernelGGL(softmax_stats_kernel, dim3((BN * NP + 255) / 256), dim3(256), 0, stream,
                       logits, mx, se, cnt);
    hipLaunchKernelGGL(per_class_nms_kernel, dim3(BN * (NC - 1)), dim3(256), 0, stream,
                       logits, regress, props, mx, se, cnt, g_key);
    hipLaunchKernelGGL(topk_kernel, dim3(BN), dim3(1024), 0, stream,
                       cnt, g_key, props, regress, out);
}

// Round 4
// 118.666 us; speedup vs baseline: 3.1181x; 1.3000x over previous
//
#include <hip/hip_runtime.h>
#include <math.h>
#include <float.h>

#define BN 2
#define NP 1024
#define NC 81
#define ND 100
#define MAXC 8192
#define CAP 1024
#define NBIN 4096
#define SCORE_T 0.05f
#define NMS_T 0.5f
#define BBOX_CLIP 4.135166556742356f   // log(1000/16)

// Decode one box, identical op order everywhere so kernel2/kernel3 results are bit-equal.
__device__ __forceinline__ void decode_box(
    const float* __restrict__ props, const float* __restrict__ regress,
    int b, int n, int c, float& x1, float& y1, float& x2, float& y2)
{
    const float* pr = props + ((size_t)b * NP + n) * 4;
    float p0 = pr[0], p1 = pr[1], p2 = pr[2], p3 = pr[3];
    float w  = p2 - p0 + 1.0f, h = p3 - p1 + 1.0f;
    float cx = p0 + 0.5f * w,  cy = p1 + 0.5f * h;
    const float* rl = regress + (((size_t)b * NP + n) * NC + c) * 4;
    float dx = rl[0] / 10.0f, dy = rl[1] / 10.0f;
    float dw = fminf(rl[2] / 5.0f, BBOX_CLIP);
    float dh = fminf(rl[3] / 5.0f, BBOX_CLIP);
    float pcx = dx * w + cx, pcy = dy * h + cy;
    float pw  = expf(dw) * w, ph = expf(dh) * h;
    x1 = pcx - 0.5f * pw; y1 = pcy - 0.5f * ph;
    x2 = pcx + 0.5f * pw - 1.0f; y2 = pcy + 0.5f * ph - 1.0f;
    x1 = fminf(fmaxf(x1, 0.f), 1023.f);
    y1 = fminf(fmaxf(y1, 0.f), 1023.f);
    x2 = fminf(fmaxf(x2, 0.f), 1023.f);
    y2 = fminf(fmaxf(y2, 0.f), 1023.f);
}

// ---------------- Kernel 1: softmax -> transposed per-class probs ----------------
// probs_t[b][cls][n], cls = class-1 (background dropped). Coalesced stores (lane=n).
__global__ __launch_bounds__(256) void softmax_probs_kernel(
    const float* __restrict__ logits, float* __restrict__ probs_t, int* __restrict__ cnt)
{
    int g = blockIdx.x * 256 + threadIdx.x;
    if (g == 0) { cnt[0] = 0; cnt[1] = 0; }
    if (g >= BN * NP) return;
    int b = g / NP, n = g % NP;
    const float* row = logits + (size_t)g * NC;
    float m = -FLT_MAX;
    for (int i = 0; i < NC; ++i) m = fmaxf(m, row[i]);
    float s = 0.f;
    for (int i = 0; i < NC; ++i) s += expf(row[i] - m);
    for (int c = 1; c < NC; ++c)
        probs_t[((size_t)b * (NC - 1) + (c - 1)) * NP + n] = expf(row[c] - m) / s;
}

// ---------------- Kernel 2: per-(image,class) filter + sort + decode + NMS ----------------
// Single wave per block: __syncthreads degenerates to waitcnt (no multi-wave barrier cost).
__global__ __launch_bounds__(64) void per_class_nms_kernel(
    const float* __restrict__ probs_t, const float* __restrict__ regress,
    const float* __restrict__ props, int* __restrict__ cnt,
    unsigned long long* __restrict__ g_key)
{
    const int b   = blockIdx.x / (NC - 1);
    const int cls = blockIdx.x % (NC - 1);   // 0..79
    const int c   = cls + 1;                 // class index in [1, 80]
    const int tid = threadIdx.x;

    __shared__ float s_score[NP];
    __shared__ int   s_idx[NP];
    __shared__ float s_x1[NP], s_y1[NP], s_x2[NP], s_y2[NP], s_area[NP];
    __shared__ int   s_keep[NP];
    __shared__ int   s_cnt;

    if (tid == 0) s_cnt = 0;
    __syncthreads();

    // --- compact candidates with prob > SCORE_T (coalesced reads) ---
    const float* prow = probs_t + ((size_t)b * (NC - 1) + cls) * NP;
    for (int n = tid; n < NP; n += 64) {
        float p = prow[n];
        if (p > SCORE_T) {
            int k = atomicAdd(&s_cnt, 1);
            s_score[k] = p;
            s_idx[k]   = n;
        }
    }
    __syncthreads();
    const int M = s_cnt;
    if (M == 0) return;

    int Mp = 1; while (Mp < M) Mp <<= 1;
    for (int i = M + tid; i < Mp; i += 64) { s_score[i] = -FLT_MAX; s_idx[i] = NP + i; }
    __syncthreads();

    // --- bitonic sort, descending by score ---
    for (int k = 2; k <= Mp; k <<= 1) {
        for (int j = k >> 1; j > 0; j >>= 1) {
            for (int i = tid; i < Mp; i += 64) {
                int ixj = i ^ j;
                if (ixj > i) {
                    bool desc = ((i & k) == 0);
                    float si = s_score[i], sj = s_score[ixj];
                    if (desc ? (si < sj) : (si > sj)) {
                        s_score[i] = sj; s_score[ixj] = si;
                        int t = s_idx[i]; s_idx[i] = s_idx[ixj]; s_idx[ixj] = t;
                    }
                }
            }
            __syncthreads();
        }
    }

    // --- decode boxes for the M live candidates ---
    for (int i = tid; i < M; i += 64) {
        int n = s_idx[i];
        float x1, y1, x2, y2;
        decode_box(props, regress, b, n, c, x1, y1, x2, y2);
        s_x1[i] = x1; s_y1[i] = y1; s_x2[i] = x2; s_y2[i] = y2;
        s_area[i] = (x2 - x1 + 1.f) * (y2 - y1 + 1.f);
        s_keep[i] = 1;
    }
    __syncthreads();

    // --- greedy NMS: i sequential, suppression parallel ---
    for (int i = 0; i < M; ++i) {
        if (s_keep[i]) {
            float x1i = s_x1[i], y1i = s_y1[i], x2i = s_x2[i], y2i = s_y2[i], ai = s_area[i];
            for (int j = i + 1 + tid; j < M; j += 64) {
                float lx = fmaxf(x1i, s_x1[j]);
                float ly = fmaxf(y1i, s_y1[j]);
                float rx = fminf(x2i, s_x2[j]);
                float ry = fminf(y2i, s_y2[j]);
                float wd = fmaxf(rx - lx + 1.f, 0.f);
                float ht = fmaxf(ry - ly + 1.f, 0.f);
                float inter = wd * ht;
                float iou = inter / (ai + s_area[j] - inter);
                if (iou > NMS_T) s_keep[j] = 0;
            }
        }
        __syncthreads();
    }

    // --- append survivor keys: (score_bits << 32) | ~flat_idx ---
    for (int i = tid; i < M; i += 64) {
        if (s_keep[i]) {
            int pos = atomicAdd(&cnt[b], 1);
            if (pos < MAXC) {
                unsigned int sb = __float_as_uint(s_score[i]);
                unsigned int f  = (unsigned int)(cls * NP + s_idx[i]);
                g_key[(size_t)b * MAXC + pos] =
                    ((unsigned long long)sb << 32) | (unsigned long long)(0xFFFFFFFFu - f);
            }
        }
    }
}

__device__ __forceinline__ void emit_slot(
    float* __restrict__ out, const float* __restrict__ props,
    const float* __restrict__ regress, int b, int d, unsigned long long key)
{
    float score = __uint_as_float((unsigned int)(key >> 32));
    float* ob = out + ((size_t)b * ND + d) * 4;
    float* os = out + (size_t)BN * ND * 4 + b * ND + d;
    float* ol = out + (size_t)BN * ND * 5 + b * ND + d;
    if (score > 0.f) {
        unsigned int f = 0xFFFFFFFFu - (unsigned int)(key & 0xFFFFFFFFu);
        int cls = f / NP, n = f % NP;
        float x1, y1, x2, y2;
        decode_box(props, regress, b, n, cls + 1, x1, y1, x2, y2);
        ob[0] = x1; ob[1] = y1; ob[2] = x2; ob[3] = y2;
        *os = score;
        *ol = (float)(cls + 1);
    } else {
        ob[0] = 0.f; ob[1] = 0.f; ob[2] = 0.f; ob[3] = 0.f;
        *os = 0.f;
        *ol = -1.f;
    }
}

// ---------------- Kernel 3: per-image top-100 via 12-bit radix-select + small sort ----------------
__global__ __launch_bounds__(256) void topk_kernel(
    const int* __restrict__ cnt, unsigned long long* __restrict__ g_key,
    const float* __restrict__ props, const float* __restrict__ regress,
    float* __restrict__ out)
{
    const int b = blockIdx.x;
    const int tid = threadIdx.x;

    __shared__ int hist[NBIN];                 // 16 KB
    __shared__ unsigned long long cbuf[CAP];   // 8 KB
    __shared__ int s_bstar, s_cnt2;

    int K = cnt[b]; if (K > MAXC) K = MAXC;
    const unsigned long long* keys = g_key + (size_t)b * MAXC;

    for (int i = tid; i < NBIN; i += 256) hist[i] = 0;
    if (tid == 0) s_cnt2 = 0;
    __syncthreads();

    for (int i = tid; i < K; i += 256)
        atomicAdd(&hist[(int)(keys[i] >> 52)], 1);
    __syncthreads();

    // wave 0: find boundary bin b* (count of bins >= b* first reaches >= ND from the top)
    if (tid < 64) {
        int l = tid;
        int gs = 0;
        for (int q = 0; q < 64; ++q) gs += hist[l * 64 + q];
        int pre = gs;                                    // inclusive prefix over lanes
        for (int off = 1; off < 64; off <<= 1) {
            int v = __shfl_up(pre, off, 64);
            if (l >= off) pre += v;
        }
        int total = __shfl(pre, 63, 64);
        int S = total - pre + gs;                        // inclusive suffix: groups >= l
        unsigned long long ball = __ballot(S >= ND);
        int gstar = ball ? (63 - __clzll((long long)ball)) : 0;
        int Sg = __shfl(S, gstar, 64);
        int Gg = __shfl(gs, gstar, 64);
        int A  = Sg - Gg;                                // keys in groups > gstar
        int h  = hist[gstar * 64 + l];
        int pre2 = h;
        for (int off = 1; off < 64; off <<= 1) {
            int v = __shfl_up(pre2, off, 64);
            if (l >= off) pre2 += v;
        }
        int T = Gg - pre2 + h;                           // suffix within group
        unsigned long long ball2 = __ballot(A + T >= ND);
        int binin = ball2 ? (63 - __clzll((long long)ball2)) : 0;
        if (l == 0) s_bstar = gstar * 64 + binin;
    }
    __syncthreads();
    const int bstar = s_bstar;

    // compact keys with bin >= b*  (superset of exact top-ND; all excluded keys are smaller)
    for (int i = tid; i < K; i += 256) {
        unsigned long long key = keys[i];
        if ((int)(key >> 52) >= bstar) {
            int p = atomicAdd(&s_cnt2, 1);
            if (p < CAP) cbuf[p] = key;
        }
    }
    __syncthreads();
    const int Tt = s_cnt2;

    if (Tt <= CAP) {
        int Tp = 128; while (Tp < Tt) Tp <<= 1;          // >= 128 so ND slots always exist
        for (int i = Tt + tid; i < Tp; i += 256) cbuf[i] = 0ull;
        __syncthreads();
        for (int k = 2; k <= Tp; k <<= 1) {
            for (int j = k >> 1; j > 0; j >>= 1) {
                for (int i = tid; i < Tp; i += 256) {
                    int ixj = i ^ j;
                    if (ixj > i) {
                        bool desc = ((i & k) == 0);
                        unsigned long long a = cbuf[i], c2 = cbuf[ixj];
                        if (desc ? (a < c2) : (a > c2)) { cbuf[i] = c2; cbuf[ixj] = a; }
                    }
                }
                __syncthreads();
            }
        }
        for (int d = tid; d < ND; d += 256)
            emit_slot(out, props, regress, b, d, cbuf[d]);
    } else {
        // fallback (statistically unreachable): ND serial argmax rounds, destructive
        __shared__ unsigned long long rk[256];
        __shared__ int rp[256];
        for (int d = 0; d < ND; ++d) {
            unsigned long long bk = 0ull; int bp = -1;
            for (int t = tid; t < K; t += 256) {
                unsigned long long k2 = g_key[(size_t)b * MAXC + t];
                if (k2 > bk) { bk = k2; bp = t; }
            }
            rk[tid] = bk; rp[tid] = bp;
            __syncthreads();
            for (int off = 128; off > 0; off >>= 1) {
                if (tid < off && rk[tid + off] > rk[tid]) {
                    rk[tid] = rk[tid + off]; rp[tid] = rp[tid + off];
                }
                __syncthreads();
            }
            if (tid == 0) {
                emit_slot(out, props, regress, b, d, rk[0]);
                if (rp[0] >= 0) g_key[(size_t)b * MAXC + rp[0]] = 0ull;
            }
            __syncthreads();
        }
    }
}

extern "C" void kernel_launch(void* const* d_in, const int* in_sizes, int n_in,
                              void* d_out, int out_size, void* d_ws, size_t ws_size,
                              hipStream_t stream) {
    const float* logits  = (const float*)d_in[0];   // [B, N, C]
    const float* regress = (const float*)d_in[1];   // [B, N, C*4]
    const float* props   = (const float*)d_in[2];   // [B, N, 4]
    float* out = (float*)d_out;                     // boxes(800) | scores(200) | labels(200)

    // Workspace layout (no overlap):
    //   [0     , 8     )  cnt     : 2 ints
    //   [256   , 655616)  probs_t : BN*(NC-1)*NP floats (640 KB)
    //   [655616, 786688)  g_key   : BN*MAXC u64 (128 KB)
    char* ws = (char*)d_ws;
    int*   cnt     = (int*)  (ws);
    float* probs_t = (float*)(ws + 256);
    unsigned long long* g_key = (unsigned long long*)(ws + 256 + (size_t)BN * (NC - 1) * NP * 4);

    hipLaunchKernelGGL(softmax_probs_kernel, dim3((BN * NP + 255) / 256), dim3(256), 0, stream,
                       logits, probs_t, cnt);
    hipLaunchKernelGGL(per_class_nms_kernel, dim3(BN * (NC - 1)), dim3(64), 0, stream,
                       probs_t, regress, props, cnt, g_key);
    hipLaunchKernelGGL(topk_kernel, dim3(BN), dim3(256), 0, stream,
                       cnt, g_key, props, regress, out);
}